// Round 13
// baseline (180.693 us; speedup 1.0000x reference)
//
#include <hip/hip_runtime.h>

// Problem constants
#define NUM_EMB 1024
#define EMB_DIM 256
#define BATCH   32
#define HW      1024
#define Z_ELEMS (BATCH*EMB_DIM*HW)   // 8388608
#define LOSS_OFF Z_ELEMS
#define IDX_OFF (Z_ELEMS+1)

// ---------------------------------------------------------------------------
// Workspace layout (ws is 256 MiB, poisoned between iterations; the ~43us
// 256MiB fill sits inside the timed loop and is the uncontrollable floor).
//   float[0]  loss accumulator     float[1](as uint) ticket
//   floats [16 .. 1040)       cnorm[1024]
//   halves [2359296..2621440) Bt — codebook*1024 fp16, MFMA-B-frag tiled (512 KB)
// Candidate lists no longer touch memory: filter+rescore+gather are fused and
// candidates live entirely in LDS.
#define WS_CNORM_OFF 16
#define WS_BT_HOFF   2359296
#define CAND_CAP  32

// Per-query filter threshold: T = T_SLOPE*S1z + T_BIAS (proof in round-1 notes:
// fp16 single pass, codebook scaled x1024 => need 3.82e-6*S1z + 1e-4; chosen
// slope/bias give 1.57x / 3x margin; s1z is a bound input only).
#define T_SLOPE 6.0e-6f
#define T_BIAS  3.0e-4f

typedef __attribute__((ext_vector_type(8))) _Float16 f16x8;
typedef __attribute__((ext_vector_type(4))) float f32x4;

// ---------------------------------------------------------------------------
// K0: tiny prep, 132 blocks: cnorm (exact pairwise tree) + Bt fp16 pack.
__global__ __launch_bounds__(256) void k_prep(const float* __restrict__ cb,
                                              float* __restrict__ ws) {
    const int tid = threadIdx.x;
    const int blk = blockIdx.x;
    if (blk == 0 && tid == 0) { ws[0] = 0.0f; ((unsigned*)ws)[1] = 0u; }
    if (blk < 4) {
        int k = blk * 256 + tid;
        const float* row = cb + (size_t)k * EMB_DIM;
        float hsum[2];
#pragma unroll
        for (int h = 0; h < 2; ++h) {
            const float* a = row + h * 128;
            float r[8];
#pragma unroll
            for (int j = 0; j < 8; ++j) r[j] = __fmul_rn(a[j], a[j]);
            for (int i = 8; i < 128; i += 8)
#pragma unroll
                for (int j = 0; j < 8; ++j)
                    r[j] = __fadd_rn(r[j], __fmul_rn(a[i + j], a[i + j]));
            hsum[h] = __fadd_rn(__fadd_rn(__fadd_rn(r[0], r[1]), __fadd_rn(r[2], r[3])),
                                __fadd_rn(__fadd_rn(r[4], r[5]), __fadd_rn(r[6], r[7])));
        }
        ws[WS_CNORM_OFF + k] = __fadd_rn(hsum[0], hsum[1]);
    } else {
        unsigned u = (unsigned)(blk - 4) * 256 + tid;   // 0..32767
        int lane = u & 63;
        int nt   = (u >> 6) & 15;
        int cc   = (u >> 10) & 7;
        int s    = (u >> 13) & 3;
        int code = s * 256 + nt * 16 + (lane & 15);
        int d0   = cc * 32 + (lane >> 4) * 8;
        const float* cr = cb + (size_t)code * EMB_DIM + d0;
        f16x8 v;
#pragma unroll
        for (int j = 0; j < 8; ++j) v[j] = (_Float16)(cr[j] * 1024.0f);
        _Float16* Bt = (_Float16*)ws + WS_BT_HOFF;
        *(f16x8*)(Bt + ((((size_t)(s * 8 + cc) * 16 + nt) * 64 + lane) * 8)) = v;
    }
}

// ---------------------------------------------------------------------------
// K1: FUSED filter + rescore + gather + loss. 1024 blocks x 32 queries.
// Rationale (r12): both old kernels are per-block phase-chain bound and each
// paid its own z acquisition. One fp32 z_lds tile now serves: A fp16
// conversion (RNE, bit-identical to the old global->fp16 path), s1z, znorm
// (exact pairwise tree), exact rescore dots, and gather. Candidates stay in
// LDS (no global cnt/cand round-trip). No cross-block dependency exists:
// each block covers all 4 slabs so block-min == global min (proof unchanged).
// MFMA structure = r10's verified 32-query layout (slot c*2+mt) at the
// known-good (256,2) VGPR cap. LDS ~64 KB -> 2 blocks/CU.
__global__ __launch_bounds__(256, 2) void k_fused(const float* __restrict__ z,
                                                  const float* __restrict__ cb,
                                                  float* __restrict__ ws,
                                                  float* __restrict__ out) {
    __shared__ __attribute__((aligned(16))) float z_lds[256][32];      // 32 KB
    __shared__ __attribute__((aligned(16))) _Float16 A_lds[1024 * 8];  // 16 KB
    __shared__ float wm[128];
    __shared__ float rmin_s[32];
    __shared__ float tq_s[32];
    __shared__ float thr_s[32];
    __shared__ int   cnt_s[32];
    __shared__ int   bidx_s[32][CAND_CAP];   // 4 KB
    __shared__ float bval_s[32][CAND_CAP];   // 4 KB
    __shared__ float zh_s[32];
    __shared__ float s1h_s[32];
    __shared__ float zn_s[32];
    __shared__ unsigned long long key_s[32];
    __shared__ int   idx_s[32];
    __shared__ int   c_s[32];
    __shared__ int   offI[32];
    __shared__ int   ovf_s[32];
    __shared__ float s_half[32][33];         // 4.2 KB
    __shared__ float s_red[4];
    __shared__ int   work_s;

    const int tid = threadIdx.x;
    const int w = tid >> 6, l = tid & 63;
    const int qb = blockIdx.x, nq0 = qb * 32;
    const int bb = nq0 >> 10, p0 = nq0 & 1023;
    const float* cn = ws + WS_CNORM_OFF;

    const f16x8* B8 = (const f16x8*)((const _Float16*)ws + WS_BT_HOFF);
    f16x8* Al = (f16x8*)A_lds;

    // B prologue: chunks 0,1 in flight under z staging
    f16x8 bq[3][4];
#pragma unroll
    for (int t = 0; t < 2; ++t)
#pragma unroll
        for (int i = 0; i < 4; ++i)
            bq[t][i] = B8[((size_t)(t * 16) + w * 4 + i) * 64 + l];

    // ---- stage z tile [256 d][32 q] fp32, float4 coalesced (exact bits) ----
    {
        const float* zb = z + (size_t)bb * EMB_DIM * HW + p0;
        const int q4 = tid & 7, g = tid >> 3;   // 8 threads/row, 32 rows/pass
#pragma unroll
        for (int r = 0; r < 8; ++r) {
            int d = r * 32 + g;
            float4 vv = *(const float4*)(zb + (size_t)d * HW + q4 * 4);
            *(float4*)&z_lds[d][q4 * 4] = vv;
        }
    }
    if (tid < 32) { cnt_s[tid] = 0; rmin_s[tid] = 3.4e38f; }
    __syncthreads();

    // ---- znorm (exact pairwise tree, 128-d seam) + s1z halves ----
    float hf0 = 0.0f, s10 = 0.0f;
    if (tid < 64) {
        const int q = l & 31, h = l >> 5;
        float r[8]; float s1 = 0.0f;
#pragma unroll
        for (int j = 0; j < 8; ++j) {
            float v = z_lds[h * 128 + j][q];
            r[j] = __fmul_rn(v, v); s1 += fabsf(v);
        }
        for (int i = 8; i < 128; i += 8)
#pragma unroll
            for (int j = 0; j < 8; ++j) {
                float v = z_lds[h * 128 + i + j][q];
                r[j] = __fadd_rn(r[j], __fmul_rn(v, v)); s1 += fabsf(v);
            }
        float hf = __fadd_rn(__fadd_rn(__fadd_rn(r[0], r[1]), __fadd_rn(r[2], r[3])),
                             __fadd_rn(__fadd_rn(r[4], r[5]), __fadd_rn(r[6], r[7])));
        if (h) { zh_s[q] = hf; s1h_s[q] = s1; } else { hf0 = hf; s10 = s1; }
    }
    // ---- A fp16 conversion from z_lds (RNE; same bits as old global path) ----
    // entry idx -> slot=idx>>6 (c=slot>>1, mt=slot&1), lane lp=idx&63;
    // element j holds A[m=mt*16+(lp&15)][d=c*32+(lp>>4)*8+j]  (r9-verified map)
#pragma unroll
    for (int e = 0; e < 4; ++e) {
        const int idx = e * 256 + tid;
        const int slot = idx >> 6, lp = idx & 63;
        const int cc = slot >> 1, mt = slot & 1;
        const int m = mt * 16 + (lp & 15), db = cc * 32 + (lp >> 4) * 8;
        f16x8 g;
#pragma unroll
        for (int j = 0; j < 8; ++j) g[j] = (_Float16)z_lds[db + j][m];
        Al[idx] = g;
    }
    __syncthreads();
    if (tid < 32) {
        zn_s[tid] = __fadd_rn(hf0, zh_s[tid]);              // exact fadd(h0,h1)
        tq_s[tid] = fmaf(T_SLOPE, s10 + s1h_s[tid], T_BIAS);
    }
    // (first consumer of zn_s/tq_s is behind the slab-epilogue barrier)

    // ---- MFMA main loop: r10 structure verbatim ----
    f32x4 acc[2][4];
#pragma unroll
    for (int mt = 0; mt < 2; ++mt)
#pragma unroll
        for (int nt = 0; nt < 4; ++nt) acc[mt][nt] = (f32x4)(0.0f);

#pragma unroll
    for (int t = 0; t < 32; ++t) {           // t = slab*8 + chunk
        const int c = t & 7, s = t >> 3;
        if (t + 2 < 32) {                    // depth-2 B prefetch
            const int t2 = t + 2;
#pragma unroll
            for (int i = 0; i < 4; ++i)
                bq[t2 % 3][i] = B8[((size_t)(t2 * 16) + w * 4 + i) * 64 + l];
        }
#pragma unroll
        for (int mt = 0; mt < 2; ++mt) {
            f16x8 av = Al[(c * 2 + mt) * 64 + l];
#pragma unroll
            for (int nt = 0; nt < 4; ++nt)
                acc[mt][nt] = __builtin_amdgcn_mfma_f32_16x16x32_f16(av, bq[t % 3][nt], acc[mt][nt], 0, 0, 0);
        }
        if (c == 7) {
            // ---- slab epilogue ----
            float c2[4];
#pragma unroll
            for (int nt = 0; nt < 4; ++nt)
                c2[nt] = cn[s * 256 + (w * 4 + nt) * 16 + (l & 15)];
            float vmin[2][4];
#pragma unroll
            for (int mt = 0; mt < 2; ++mt)
#pragma unroll
                for (int reg = 0; reg < 4; ++reg) vmin[mt][reg] = 3.4e38f;
#pragma unroll
            for (int mt = 0; mt < 2; ++mt)
#pragma unroll
                for (int nt = 0; nt < 4; ++nt)
#pragma unroll
                    for (int reg = 0; reg < 4; ++reg) {
                        float sv = fmaf(-0.001953125f, acc[mt][nt][reg], c2[nt]);  // -2/1024
                        acc[mt][nt][reg] = sv;
                        vmin[mt][reg] = fminf(vmin[mt][reg], sv);
                    }
#pragma unroll
            for (int msk = 1; msk < 16; msk <<= 1)
#pragma unroll
                for (int mt = 0; mt < 2; ++mt)
#pragma unroll
                    for (int reg = 0; reg < 4; ++reg)
                        vmin[mt][reg] = fminf(vmin[mt][reg], __shfl_xor(vmin[mt][reg], msk, 64));
            if ((l & 15) == 0) {
#pragma unroll
                for (int mt = 0; mt < 2; ++mt)
#pragma unroll
                    for (int reg = 0; reg < 4; ++reg)
                        wm[w * 32 + mt * 16 + (l >> 4) * 4 + reg] = vmin[mt][reg];
            }
            __syncthreads();
            if (tid < 32) {
                float smin = fminf(fminf(wm[tid], wm[32 + tid]),
                                   fminf(wm[64 + tid], wm[96 + tid]));
                float rm = fminf(rmin_s[tid], smin);
                rmin_s[tid] = rm;
                thr_s[tid] = rm + tq_s[tid];
            }
            __syncthreads();
            // append candidates under running threshold
#pragma unroll
            for (int mt = 0; mt < 2; ++mt)
#pragma unroll
                for (int reg = 0; reg < 4; ++reg) {
                    int m = mt * 16 + (l >> 4) * 4 + reg;
                    float th = thr_s[m];
#pragma unroll
                    for (int nt = 0; nt < 4; ++nt) {
                        float sv = acc[mt][nt][reg];
                        if (sv <= th) {
                            int kg = s * 256 + (w * 4 + nt) * 16 + (l & 15);
                            int pos = atomicAdd(&cnt_s[m], 1);
                            if (pos < CAND_CAP) { bidx_s[m][pos] = kg; bval_s[m][pos] = sv; }
                        }
                    }
                }
            // re-zero accumulators for next slab
#pragma unroll
            for (int mt = 0; mt < 2; ++mt)
#pragma unroll
                for (int nt = 0; nt < 4; ++nt) acc[mt][nt] = (f32x4)(0.0f);
        }
    }
    __syncthreads();   // all appends + final thr_s visible

    // ---- resolution: prune to global-min+T in LDS, prefix scan, work flag ----
    if (tid < 64) {
        int cc2 = 0, ov = 0;
        if (l < 32) {
            int c = cnt_s[l];
            float th = thr_s[l];          // global min + tq (after slab 3)
            if (c > CAND_CAP) ov = 1;
            else {
                int m = 0;
                for (int j = 0; j < c; ++j)
                    if (bval_s[l][j] <= th) bidx_s[l][m++] = bidx_s[l][j];  // in-place, m<=j
                if (m == 1) idx_s[l] = bidx_s[l][0];
                else cc2 = m;             // m>=2 (m==0 impossible: min passes)
            }
            ovf_s[l] = ov; c_s[l] = cc2; key_s[l] = ~0ULL;
        }
        int v = cc2;
#pragma unroll
        for (int off = 1; off < 64; off <<= 1) {
            int u = __shfl_up(v, off, 64);
            if (l >= off) v += u;
        }
        if (l < 32) offI[l] = v;
        unsigned long long ball = __ballot(ov != 0);
        if (l == 63) work_s = v + (ball ? 1 : 0);
    }
    __syncthreads();

    if (work_s != 0) {
        // candidate-per-thread exact rescore (bit-proven recipe)
        const int C = offI[31];
        for (int t = tid; t < C; t += 256) {
            int lo = 0, hi = 31;
            while (lo < hi) { int mid = (lo + hi) >> 1; if (offI[mid] > t) hi = mid; else lo = mid + 1; }
            const int m = lo;
            const int j = t - (m ? offI[m - 1] : 0);
            const int kk = bidx_s[m][j];
            const float* r = cb + (size_t)kk * EMB_DIM;
            float dot = 0.0f;
#pragma unroll 8
            for (int d = 0; d < EMB_DIM; ++d)
                dot = fmaf(z_lds[d][m], r[d], dot);
            float t1 = __fadd_rn(zn_s[m], cn[kk]);
            float sv = __fadd_rn(t1, __fmul_rn(-2.0f, dot));
            unsigned ue = __float_as_uint(sv);
            ue = (ue >> 31) ? ~ue : (ue | 0x80000000u);
            atomicMin(&key_s[m], ((unsigned long long)ue << 32) | (unsigned)kk);
        }
        // overflow queries (rare): distributed exact full scan, wave per query
        for (int m = w; m < 32; m += 4) {
            if (!ovf_s[m]) continue;
            const float z2 = zn_s[m];
            float sv = 3.4e38f; int kk = NUM_EMB;
            for (int k0 = l; k0 < NUM_EMB; k0 += 64) {
                const float* r = cb + (size_t)k0 * EMB_DIM;
                float dot = 0.0f;
#pragma unroll 8
                for (int d = 0; d < EMB_DIM; ++d)
                    dot = fmaf(z_lds[d][m], r[d], dot);
                float t1 = __fadd_rn(z2, cn[k0]);
                float s2 = __fadd_rn(t1, __fmul_rn(-2.0f, dot));
                if (s2 < sv) { sv = s2; kk = k0; }   // ascending k: < keeps first
            }
#pragma unroll
            for (int off = 32; off; off >>= 1) {
                float osv = __shfl_xor(sv, off, 64);
                int   okk = __shfl_xor(kk, off, 64);
                if (osv < sv || (osv == sv && okk < kk)) { sv = osv; kk = okk; }
            }
            if (l == 0) {
                unsigned ue = __float_as_uint(sv);
                ue = (ue >> 31) ? ~ue : (ue | 0x80000000u);
                key_s[m] = ((unsigned long long)ue << 32) | (unsigned)kk;
            }
        }
        __syncthreads();
        if (tid < 32 && (c_s[tid] > 0 || ovf_s[tid]))
            idx_s[tid] = (int)(unsigned)(key_s[tid] & 0xFFFFFFFFULL);
    }
    if (tid < 32) out[IDX_OFF + nq0 + tid] = (float)idx_s[tid];
    __syncthreads();   // idx_s visible to all for gather

    // ---- gather (r12-passing code verbatim): zv from z_lds, cb via s_half ----
    const int p   = tid & 31;         // query within block
    const int cg  = tid >> 5;         // 0..7: 4-d group within the 32-d half
    const int row = tid >> 3;         // 0..31: staging row (query)
    const int col = (tid & 7) * 4;    // staging col group
    float* orow = out + (size_t)bb * EMB_DIM * HW + p0 + p;

    float acc2 = 0.0f;
#pragma unroll 1
    for (int d0 = 0; d0 < EMB_DIM; d0 += 64) {
#pragma unroll 1
        for (int h = 0; h < 2; ++h) {
            const float* cr = cb + (size_t)idx_s[row] * EMB_DIM + d0 + h * 32;
            *(float4*)&s_half[row][col] = *(const float4*)(cr + col);
            __syncthreads();
#pragma unroll
            for (int j0 = 0; j0 < 4; ++j0) {
                int c32 = cg * 4 + j0;
                int d   = d0 + h * 32 + c32;
                float zq = s_half[p][c32];
                float zv = z_lds[d][p];
                float df = zq - zv;
                orow[(size_t)d * HW] = zv + df;
                acc2 += df * df;
            }
            __syncthreads();
        }
    }
#pragma unroll
    for (int off = 32; off > 0; off >>= 1) acc2 += __shfl_down(acc2, off, 64);
    if ((tid & 63) == 0) s_red[tid >> 6] = acc2;
    __syncthreads();
    if (tid == 0) {
        atomicAdd(ws, s_red[0] + s_red[1] + s_red[2] + s_red[3]);
        __threadfence();
        unsigned old = atomicAdd((unsigned int*)ws + 1, 1u);
        if (old == 1023u) {
            float total = atomicAdd(ws, 0.0f);
            out[LOSS_OFF] = 1.25f * (total * (1.0f / 8388608.0f));
        }
    }
}

// ---------------------------------------------------------------------------
extern "C" void kernel_launch(void* const* d_in, const int* in_sizes, int n_in,
                              void* d_out, int out_size, void* d_ws, size_t ws_size,
                              hipStream_t stream) {
    const float* z  = (const float*)d_in[0];
    const float* cb = (const float*)d_in[1];
    float* out = (float*)d_out;
    float* ws  = (float*)d_ws;

    k_prep <<<132,  256, 0, stream>>>(cb, ws);
    k_fused<<<1024, 256, 0, stream>>>(z, cb, ws, out);
}

// Round 15
// 156.607 us; speedup vs baseline: 1.1538x; 1.1538x over previous
//
#include <hip/hip_runtime.h>

// Problem constants
#define NUM_EMB 1024
#define EMB_DIM 256
#define BATCH   32
#define HW      1024
#define Z_ELEMS (BATCH*EMB_DIM*HW)   // 8388608
#define LOSS_OFF Z_ELEMS
#define IDX_OFF (Z_ELEMS+1)

// ---------------------------------------------------------------------------
// FINAL CONFIGURATION — exact revert to round 7 (best measured: 157.9 us).
// Refuted alternatives (kept for the record):
//   r10: 1024x32q filter grid        -> 164 (2x Bt L2 traffic, no gain)
//   r11: LDS-bulk B staging          -> 166 (extra barriers, no gain)
//   r12: 1024x32q resgather          -> 174 (phase chain is per-block fixed)
//   r13: full filter+resgather fuse  -> 181 (serialized phases, bank conflicts)
// VGPR-cap law (filter): (256,3)->84 VGPR->110us, (256,2)->100->44us,
// (256,4)->64->142us(prof, spilled). (256,2) is the only safe point.
// Timed-loop floor: harness 256MiB ws re-poison ~43us + out memset ~5us.
// (r14 submission of this exact source hit an infra failure — resubmitted.)
//
// Workspace layout (ws is 256 MiB, poisoned between iterations).
//   float[0]  loss accumulator     float[1](as uint) ticket
//   floats [16    .. 1040)   cnorm[1024]
//   ints   [69632 .. 102400) cand_cnt[32768]  (0 resolved, 1025 overflow)
//   ints   [102400..1150976) cand_idx[32768][32] compacted survivors
//   halves [2359296..2621440) Bt — codebook*1024 fp16, MFMA-B-frag tiled (512 KB)
#define WS_CNORM_OFF 16
#define WS_CNT_IOFF  69632
#define WS_CAND_IOFF 102400
#define WS_BT_HOFF   2359296
#define CAND_CAP  32

// Per-query filter threshold: T = T_SLOPE*S1z + T_BIAS (proof in round-1 notes:
// fp16 single pass, codebook scaled x1024 => need 3.82e-6*S1z + 1e-4; chosen
// slope/bias give 1.57x / 3x margin; s1z is a bound input only).
#define T_SLOPE 6.0e-6f
#define T_BIAS  3.0e-4f

typedef __attribute__((ext_vector_type(8))) _Float16 f16x8;
typedef __attribute__((ext_vector_type(4))) float f32x4;

// ---------------------------------------------------------------------------
// K0: tiny prep, 132 blocks: cnorm (exact pairwise tree) + Bt fp16 pack.
__global__ __launch_bounds__(256) void k_prep(const float* __restrict__ cb,
                                              float* __restrict__ ws) {
    const int tid = threadIdx.x;
    const int blk = blockIdx.x;
    if (blk == 0 && tid == 0) { ws[0] = 0.0f; ((unsigned*)ws)[1] = 0u; }
    if (blk < 4) {
        int k = blk * 256 + tid;
        const float* row = cb + (size_t)k * EMB_DIM;
        float hsum[2];
#pragma unroll
        for (int h = 0; h < 2; ++h) {
            const float* a = row + h * 128;
            float r[8];
#pragma unroll
            for (int j = 0; j < 8; ++j) r[j] = __fmul_rn(a[j], a[j]);
            for (int i = 8; i < 128; i += 8)
#pragma unroll
                for (int j = 0; j < 8; ++j)
                    r[j] = __fadd_rn(r[j], __fmul_rn(a[i + j], a[i + j]));
            hsum[h] = __fadd_rn(__fadd_rn(__fadd_rn(r[0], r[1]), __fadd_rn(r[2], r[3])),
                                __fadd_rn(__fadd_rn(r[4], r[5]), __fadd_rn(r[6], r[7])));
        }
        ws[WS_CNORM_OFF + k] = __fadd_rn(hsum[0], hsum[1]);
    } else {
        unsigned u = (unsigned)(blk - 4) * 256 + tid;   // 0..32767
        int lane = u & 63;
        int nt   = (u >> 6) & 15;
        int cc   = (u >> 10) & 7;
        int s    = (u >> 13) & 3;
        int code = s * 256 + nt * 16 + (lane & 15);
        int d0   = cc * 32 + (lane >> 4) * 8;
        const float* cr = cb + (size_t)code * EMB_DIM + d0;
        f16x8 v;
#pragma unroll
        for (int j = 0; j < 8; ++j) v[j] = (_Float16)(cr[j] * 1024.0f);
        _Float16* Bt = (_Float16*)ws + WS_BT_HOFF;
        *(f16x8*)(Bt + ((((size_t)(s * 8 + cc) * 16 + nt) * 64 + lane) * 8)) = v;
    }
}

// ---------------------------------------------------------------------------
// K1: MFMA candidate filter — round-7 version verbatim. 512 blocks x 64
// queries, all 4 slabs per block (block-min == global min), per-lane depth-2
// B prefetch, A staged directly from fp32 z with in-kernel s1z.
__global__ __launch_bounds__(256, 2) void k_filter(const float* __restrict__ z,
                                                   float* __restrict__ ws,
                                                   float* __restrict__ out) {
    __shared__ __attribute__((aligned(16))) _Float16 A_lds[2048 * 8];  // 32 KB
    __shared__ float wm[256];
    __shared__ float rmin_s[64];
    __shared__ float tq_s[64];
    __shared__ float thr_s[64];
    __shared__ int   cnt_s[64];
    __shared__ int   bidx_s[64][CAND_CAP];   // 8 KB
    __shared__ float bval_s[64][CAND_CAP];   // 8 KB

    const int tid = threadIdx.x;
    const int w = tid >> 6, l = tid & 63;
    const int qb = blockIdx.x, nq0 = qb * 64;
    const int bb = nq0 >> 10, p0 = nq0 & 1023;

    const f16x8* B8 = (const f16x8*)((const _Float16*)ws + WS_BT_HOFF);
    f16x8* Al = (f16x8*)A_lds;

    // prologue: issue B loads for steps 0,1 so they fly under A staging
    f16x8 b[3][4];
#pragma unroll
    for (int t = 0; t < 2; ++t)
#pragma unroll
        for (int nt = 0; nt < 4; ++nt)
            b[t][nt] = B8[((size_t)(t * 16) + w * 4 + nt) * 64 + l];

    // stage A from fp32 z + s1 partial
    {
        const float* zq = z + (size_t)bb * EMB_DIM * HW + p0 + l;
        float s1p = 0.0f;
#pragma unroll
        for (int i8 = 0; i8 < 8; ++i8) {
            const int d0 = w * 64 + i8 * 8;
            float v[8];
#pragma unroll
            for (int j = 0; j < 8; ++j) v[j] = zq[(size_t)(d0 + j) * HW];
            f16x8 g;
#pragma unroll
            for (int j = 0; j < 8; ++j) { g[j] = (_Float16)v[j]; s1p += fabsf(v[j]); }
            const int c = d0 >> 5, kh = (d0 >> 3) & 3;
            Al[(c * 4 + (l >> 4)) * 64 + kh * 16 + (l & 15)] = g;
        }
        wm[tid] = s1p;
    }
    if (tid < 64) { cnt_s[tid] = 0; rmin_s[tid] = 3.4e38f; }
    __syncthreads();
    if (tid < 64)
        tq_s[tid] = fmaf(T_SLOPE,
                         __fadd_rn(__fadd_rn(wm[tid], wm[64 + tid]),
                                   __fadd_rn(wm[128 + tid], wm[192 + tid])),
                         T_BIAS);
    __syncthreads();

    const float* cn = ws + WS_CNORM_OFF;
    f32x4 acc[4][4];
#pragma unroll
    for (int mt = 0; mt < 4; ++mt)
#pragma unroll
        for (int nt = 0; nt < 4; ++nt) acc[mt][nt] = (f32x4)(0.0f);

#pragma unroll
    for (int t = 0; t < 32; ++t) {           // t = slab*8 + chunk
        const int c = t & 7, s = t >> 3;
        if (t + 2 < 32) {                    // depth-2 B prefetch
            const int t2 = t + 2;
#pragma unroll
            for (int nt = 0; nt < 4; ++nt)
                b[t2 % 3][nt] = B8[((size_t)(t2 * 16) + w * 4 + nt) * 64 + l];
        }
#pragma unroll
        for (int mt = 0; mt < 4; ++mt) {
            f16x8 av = Al[(c * 4 + mt) * 64 + l];
#pragma unroll
            for (int nt = 0; nt < 4; ++nt)
                acc[mt][nt] = __builtin_amdgcn_mfma_f32_16x16x32_f16(av, b[t % 3][nt], acc[mt][nt], 0, 0, 0);
        }
        if (c == 7) {
            // ---- slab epilogue (B loads for next slab already in flight) ----
            float c2[4];
#pragma unroll
            for (int nt = 0; nt < 4; ++nt)
                c2[nt] = cn[s * 256 + (w * 4 + nt) * 16 + (l & 15)];
            float vmin[4][4];
#pragma unroll
            for (int mt = 0; mt < 4; ++mt)
#pragma unroll
                for (int reg = 0; reg < 4; ++reg) vmin[mt][reg] = 3.4e38f;
#pragma unroll
            for (int mt = 0; mt < 4; ++mt)
#pragma unroll
                for (int nt = 0; nt < 4; ++nt)
#pragma unroll
                    for (int reg = 0; reg < 4; ++reg) {
                        float sv = fmaf(-0.001953125f, acc[mt][nt][reg], c2[nt]);  // -2/1024
                        acc[mt][nt][reg] = sv;
                        vmin[mt][reg] = fminf(vmin[mt][reg], sv);
                    }
#pragma unroll
            for (int msk = 1; msk < 16; msk <<= 1)
#pragma unroll
                for (int mt = 0; mt < 4; ++mt)
#pragma unroll
                    for (int reg = 0; reg < 4; ++reg)
                        vmin[mt][reg] = fminf(vmin[mt][reg], __shfl_xor(vmin[mt][reg], msk, 64));
            if ((l & 15) == 0) {
#pragma unroll
                for (int mt = 0; mt < 4; ++mt)
#pragma unroll
                    for (int reg = 0; reg < 4; ++reg)
                        wm[w * 64 + mt * 16 + (l >> 4) * 4 + reg] = vmin[mt][reg];
            }
            __syncthreads();
            if (tid < 64) {
                float smin = fminf(fminf(wm[tid], wm[64 + tid]),
                                   fminf(wm[128 + tid], wm[192 + tid]));
                float rm = fminf(rmin_s[tid], smin);
                rmin_s[tid] = rm;
                thr_s[tid] = rm + tq_s[tid];
            }
            __syncthreads();
            // append candidates under running threshold
#pragma unroll
            for (int mt = 0; mt < 4; ++mt)
#pragma unroll
                for (int reg = 0; reg < 4; ++reg) {
                    int m = mt * 16 + (l >> 4) * 4 + reg;
                    float th = thr_s[m];
#pragma unroll
                    for (int nt = 0; nt < 4; ++nt) {
                        float sv = acc[mt][nt][reg];
                        if (sv <= th) {
                            int kg = s * 256 + (w * 4 + nt) * 16 + (l & 15);
                            int pos = atomicAdd(&cnt_s[m], 1);
                            if (pos < CAND_CAP) { bidx_s[m][pos] = kg; bval_s[m][pos] = sv; }
                        }
                    }
                }
            // re-zero accumulators for next slab
#pragma unroll
            for (int mt = 0; mt < 4; ++mt)
#pragma unroll
                for (int nt = 0; nt < 4; ++nt) acc[mt][nt] = (f32x4)(0.0f);
        }
    }
    __syncthreads();   // all appends visible
    if (tid < 64) {
        int n = nq0 + tid;
        int c = cnt_s[tid];
        int* cnt_g  = (int*)ws + WS_CNT_IOFF;
        int* cand_g = (int*)ws + WS_CAND_IOFF;
        if (c > CAND_CAP) {
            cnt_g[n] = 1025;                  // overflow sentinel -> full rescan
        } else {
            float th = thr_s[tid];            // global min + T (after slab 3)
            int m = 0, keep = 0;
            for (int j = 0; j < c; ++j) {
                if (bval_s[tid][j] <= th) {
                    cand_g[(size_t)n * CAND_CAP + m] = bidx_s[tid][j];
                    if (m == 0) keep = bidx_s[tid][j];
                    ++m;
                }
            }
            if (m == 1) {
                out[IDX_OFF + n] = (float)keep;   // resolved here
                cnt_g[n] = 0;
            } else {
                cnt_g[n] = m;
            }
        }
    }
}

// ---------------------------------------------------------------------------
// K2: fused exact znorm + rescore + gather + loss. (round-5/7 version verbatim)
__global__ __launch_bounds__(256) void k_resgather(const float* __restrict__ z,
                                                   const float* __restrict__ cb,
                                                   float* __restrict__ ws,
                                                   float* __restrict__ out) {
    __shared__ __attribute__((aligned(16))) float z_lds[256][64];   // 64 KB
    __shared__ float s_half[64][33];                                // 8.4 KB
    __shared__ int   idx_s[64];
    __shared__ int   c_s[64];
    __shared__ int   offI[64];
    __shared__ int   ovf_s[64];
    __shared__ float zh_s[64];
    __shared__ float zn_s[64];
    __shared__ unsigned long long key_s[64];
    __shared__ float s_red[4];
    __shared__ int   work_s;

    const int tid = threadIdx.x;
    const int w = tid >> 6, l = tid & 63;
    const int n0 = blockIdx.x * 64;
    const int b = n0 >> 10, p0 = n0 & 1023;
    const int* cnt  = (const int*)ws + WS_CNT_IOFF;
    const int* cand = (const int*)ws + WS_CAND_IOFF;
    const float* cn = ws + WS_CNORM_OFF;

    if (tid < 64) {   // wave 0: per-query state + prefix scan + work flag
        int c = cnt[n0 + tid];
        int ov = (c > CAND_CAP) ? 1 : 0;
        ovf_s[tid] = ov;
        int cc = (ov || c < 2) ? 0 : c;
        c_s[tid] = cc;
        key_s[tid] = ~0ULL;
        if (cc == 0 && !ov) idx_s[tid] = (int)out[IDX_OFF + n0 + tid];  // filter-resolved
        int v = cc;
#pragma unroll
        for (int off = 1; off < 64; off <<= 1) {
            int u = __shfl_up(v, off, 64);
            if (l >= off) v += u;
        }
        offI[tid] = v;
        unsigned long long ball = __ballot(ov != 0);
        if (tid == 63) work_s = v + (ball ? 1 : 0);
    }

    // stage z tile: [d][q] fp32, float4 coalesced (exact bits); always needed
    {
        const float* zb = z + (size_t)b * EMB_DIM * HW + p0;
        const int q4 = tid & 15, g = tid >> 4;
#pragma unroll 4
        for (int r = 0; r < 16; ++r) {
            int d = r * 16 + g;
            float4 vv = *(const float4*)(zb + (size_t)d * HW + q4 * 4);
            *(float4*)&z_lds[d][q4 * 4] = vv;
        }
    }
    __syncthreads();

    if (work_s != 0) {
        // znorm from z_lds: exact pairwise tree, 2 threads/query (128-d seam)
        float hf0 = 0.0f;
        if (tid < 128) {
            const int q = tid & 63, h = tid >> 6;
            float r[8];
#pragma unroll
            for (int j = 0; j < 8; ++j) {
                float v = z_lds[h * 128 + j][q];
                r[j] = __fmul_rn(v, v);
            }
            for (int i = 8; i < 128; i += 8)
#pragma unroll
                for (int j = 0; j < 8; ++j) {
                    float v = z_lds[h * 128 + i + j][q];
                    r[j] = __fadd_rn(r[j], __fmul_rn(v, v));
                }
            float hf = __fadd_rn(__fadd_rn(__fadd_rn(r[0], r[1]), __fadd_rn(r[2], r[3])),
                                 __fadd_rn(__fadd_rn(r[4], r[5]), __fadd_rn(r[6], r[7])));
            if (h) zh_s[q] = hf; else hf0 = hf;
        }
        __syncthreads();
        if (tid < 64) zn_s[tid] = __fadd_rn(hf0, zh_s[tid]);   // exact fadd(half0, half1)
        __syncthreads();

        // candidate-per-thread exact rescore
        const int C = offI[63];
        for (int t = tid; t < C; t += 256) {
            int lo = 0, hi = 63;
            while (lo < hi) { int mid = (lo + hi) >> 1; if (offI[mid] > t) hi = mid; else lo = mid + 1; }
            const int m = lo;
            const int j = t - (m ? offI[m - 1] : 0);
            const int n = n0 + m;
            const int kk = cand[(size_t)n * CAND_CAP + j];
            const float* r = cb + (size_t)kk * EMB_DIM;
            float dot = 0.0f;
#pragma unroll 8
            for (int d = 0; d < EMB_DIM; ++d)
                dot = fmaf(z_lds[d][m], r[d], dot);
            float t1 = __fadd_rn(zn_s[m], cn[kk]);
            float sv = __fadd_rn(t1, __fmul_rn(-2.0f, dot));
            unsigned ue = __float_as_uint(sv);
            ue = (ue >> 31) ? ~ue : (ue | 0x80000000u);
            atomicMin(&key_s[m], ((unsigned long long)ue << 32) | (unsigned)kk);
        }

        // overflow queries (rare): distributed exact full scan, wave per query
        for (int m = w; m < 64; m += 4) {
            if (!ovf_s[m]) continue;
            const float z2 = zn_s[m];
            float sv = 3.4e38f; int kk = NUM_EMB;
            for (int k0 = l; k0 < NUM_EMB; k0 += 64) {
                const float* r = cb + (size_t)k0 * EMB_DIM;
                float dot = 0.0f;
#pragma unroll 8
                for (int d = 0; d < EMB_DIM; ++d)
                    dot = fmaf(z_lds[d][m], r[d], dot);
                float t1 = __fadd_rn(z2, cn[k0]);
                float s2 = __fadd_rn(t1, __fmul_rn(-2.0f, dot));
                if (s2 < sv) { sv = s2; kk = k0; }   // ascending k: < keeps first
            }
#pragma unroll
            for (int off = 32; off; off >>= 1) {
                float osv = __shfl_xor(sv, off, 64);
                int   okk = __shfl_xor(kk, off, 64);
                if (osv < sv || (osv == sv && okk < kk)) { sv = osv; kk = okk; }
            }
            if (l == 0) {
                unsigned ue = __float_as_uint(sv);
                ue = (ue >> 31) ? ~ue : (ue | 0x80000000u);
                key_s[m] = ((unsigned long long)ue << 32) | (unsigned)kk;
            }
        }
        __syncthreads();
        if (tid < 64 && (c_s[tid] > 0 || ovf_s[tid])) {
            int kk = (int)(unsigned)(key_s[tid] & 0xFFFFFFFFULL);
            idx_s[tid] = kk;
            out[IDX_OFF + n0 + tid] = (float)kk;
        }
        __syncthreads();
    }

    // ---- gather phase: per-thread arithmetic/order bit-identical ----
    const int p    = tid & 63;
    const int cgrp = tid >> 6;
    const int row  = tid >> 2;
    const int q4g  = tid & 3;
    float* orow = out + (size_t)b * EMB_DIM * HW + p0 + p;

    float acc = 0.0f;
#pragma unroll 1
    for (int d0 = 0; d0 < EMB_DIM; d0 += 64) {
        const float* cr = cb + (size_t)idx_s[row] * EMB_DIM + d0;
#pragma unroll 1
        for (int h = 0; h < 2; ++h) {
#pragma unroll
            for (int pass = 0; pass < 2; ++pass) {
                int s = q4g + pass * 4;
                int gg = s >> 1, j00 = (s & 1) * 4;
                *(float4*)&s_half[row][gg * 8 + j00] = *(const float4*)(cr + gg * 16 + h * 8 + j00);
            }
            __syncthreads();
#pragma unroll
            for (int j0 = 0; j0 < 8; ++j0) {
                int c = cgrp * 16 + h * 8 + j0;
                float zq = s_half[p][cgrp * 8 + j0];
                float zv = z_lds[d0 + c][p];
                float d  = zq - zv;
                orow[(size_t)(d0 + c) * HW] = zv + d;
                acc += d * d;
            }
            __syncthreads();
        }
    }
#pragma unroll
    for (int off = 32; off > 0; off >>= 1) acc += __shfl_down(acc, off, 64);
    if ((tid & 63) == 0) s_red[tid >> 6] = acc;
    __syncthreads();
    if (tid == 0) {
        atomicAdd(ws, s_red[0] + s_red[1] + s_red[2] + s_red[3]);
        __threadfence();
        unsigned old = atomicAdd((unsigned int*)ws + 1, 1u);
        if (old == 511u) {
            float total = atomicAdd(ws, 0.0f);
            out[LOSS_OFF] = 1.25f * (total * (1.0f / 8388608.0f));
        }
    }
}

// ---------------------------------------------------------------------------
extern "C" void kernel_launch(void* const* d_in, const int* in_sizes, int n_in,
                              void* d_out, int out_size, void* d_ws, size_t ws_size,
                              hipStream_t stream) {
    const float* z  = (const float*)d_in[0];
    const float* cb = (const float*)d_in[1];
    float* out = (float*)d_out;
    float* ws  = (float*)d_ws;

    k_prep     <<<132, 256, 0, stream>>>(cb, ws);
    k_filter   <<<512, 256, 0, stream>>>(z, ws, out);
    k_resgather<<<512, 256, 0, stream>>>(z, cb, ws, out);
}